// Round 7
// baseline (961.037 us; speedup 1.0000x reference)
//
#include <hip/hip_runtime.h>
#include <hip/hip_bf16.h>

typedef __bf16 bf16x8 __attribute__((ext_vector_type(8)));
typedef __bf16 bf16x4 __attribute__((ext_vector_type(4)));
typedef float  f32x4  __attribute__((ext_vector_type(4)));

#define MFMA16(a, b, c) __builtin_amdgcn_mfma_f32_16x16x32_bf16((a), (b), (c), 0, 0, 0)

// async global->LDS DMA, 16B per lane, LDS dest = uniform base + lane*16
#define GLD_LDS16(g, l) \
  __builtin_amdgcn_global_load_lds((const __attribute__((address_space(1))) void*)(g), \
                                   (__attribute__((address_space(3))) void*)(l), 16, 0, 0)

// ---------------------------------------------------------------------------
// K1: blocks 0-47 conv-weight pack; 48-239 lin_w hi/lo pack; 240 scan of
// sizes; 241+ stream-convert x f32 -> bf16 (xb).
// B-frag for 16x16x32: lane holds B[k = (lane>>4)*8 + j][n = lane&15], j=0..7.
// ---------------------------------------------------------------------------
__global__ void k_prep(const int* __restrict__ sizes, int* __restrict__ offsets,
                       const float* __restrict__ w0, const float* __restrict__ w1,
                       const float* __restrict__ w2, const float* __restrict__ lw,
                       const float* __restrict__ x, __bf16* __restrict__ xb, int nx,
                       __bf16* __restrict__ Wpack,
                       __bf16* __restrict__ Lhi, __bf16* __restrict__ Llo) {
  const int bid = blockIdx.x, t = threadIdx.x;
  if (bid >= 241) {
    const int n4 = nx >> 2;
    int i = (bid - 241) * 256 + t;
    const int stride = (gridDim.x - 241) * 256;
    for (; i < n4; i += stride) {
      const float4 v = *(const float4*)(x + (size_t)i * 4);
      bf16x4 h; h[0] = (__bf16)v.x; h[1] = (__bf16)v.y;
                h[2] = (__bf16)v.z; h[3] = (__bf16)v.w;
      *(bf16x4*)&xb[(size_t)i * 4] = h;
    }
  } else if (bid == 240) {
    __shared__ int part[256];
    const int base = t * 32;
    int v[32];
    int s = 0;
#pragma unroll
    for (int i = 0; i < 32; ++i) { v[i] = sizes[base + i]; s += v[i]; }
    part[t] = s;
    __syncthreads();
    for (int d = 1; d < 256; d <<= 1) {
      int add = (t >= d) ? part[t - d] : 0;
      __syncthreads();
      part[t] += add;
      __syncthreads();
    }
    int run = (t == 0) ? 0 : part[t - 1];
#pragma unroll
    for (int i = 0; i < 32; ++i) { offsets[base + i] = run; run += v[i]; }
  } else if (bid < 48) {
    const int nt = bid, sl = nt >> 3, f = nt & 7;
    const int kt = t >> 6, lane = t & 63;
    const float* src; int kw, jj;
    if      (sl == 0) { src = w0; kw = 1; jj = 0; }
    else if (sl == 1) { src = w1; kw = 2; jj = 0; }
    else if (sl == 2) { src = w1; kw = 2; jj = 1; }
    else if (sl == 3) { src = w2; kw = 3; jj = 0; }
    else if (sl == 4) { src = w2; kw = 3; jj = 1; }
    else              { src = w2; kw = 3; jj = 2; }
    const int feat  = f * 16 + (lane & 15);
    const int cbase = kt * 32 + ((lane >> 4) << 3);
    __bf16* dst = Wpack + ((((nt * 4 + kt) << 6) + lane) << 3);
#pragma unroll
    for (int j = 0; j < 8; ++j)
      dst[j] = (__bf16)src[(feat * 128 + cbase + j) * kw + jj];
  } else {
    const int idx = (bid - 48) * 256 + t;          // 0..49151
    const int j = idx & 7, lane = (idx >> 3) & 63, rest = idx >> 9;  // 0..95
    const int kt = rest % 12, nt = rest / 12;
    const int o = nt * 16 + (lane & 15);
    const int q = kt * 32 + ((lane >> 4) << 3) + j;
    const float v = lw[o * 384 + q];
    const __bf16 hi = (__bf16)v;
    Lhi[idx] = hi;
    Llo[idx] = (__bf16)(v - (float)hi);
  }
}

// ---------------------------------------------------------------------------
// K2: fused conv + relu + ragged max.  1024 blocks x 8 segments, 256 threads.
// Ping-pong LDS buffers (66 rows x 128 bf16, XOR-swizzled cb^(r&7) for
// conflict-free ds_read_b128).  Staging = global_load_lds DMA issued AFTER
// the segment barrier into the vacated buffer -> the barrier never drains
// the prefetch; staging latency hidden behind the previous segment's MFMAs.
// Validity via sentinel acc-init (-1e30 on rows >= s-p): garbage/duplicate
// rows need no zero-fill (finite values never win the max).
// C/D layout (m89-verified): col = lane&15, row = (lane>>4)*4 + reg.
// ---------------------------------------------------------------------------
__global__ __launch_bounds__(256, 4)
void k_conv(const __bf16* __restrict__ xb, const int* __restrict__ sizes,
            const int* __restrict__ offsets, int Tm1,
            const float* __restrict__ cb0, const float* __restrict__ cb1,
            const float* __restrict__ cb2,
            const bf16x8* __restrict__ Wpack,
            __bf16* __restrict__ Phi, __bf16* __restrict__ Plo) {
  __shared__ __bf16 xs[2 * 66 * 128];   // two 66-row buffers, 33 KB
  const int t = threadIdx.x;
  const int wid = t >> 6, lane = t & 63;
  const int lo16 = lane & 15, g16 = lane >> 4;
  const int b0 = blockIdx.x << 3;

  // zero rows 64,65 of both buffers once (tap overreach; must be non-NaN;
  // never DMA-written so they stay zero)
  if (t < 64) {
    const int buf = t >> 5, row = 64 + ((t >> 4) & 1), sl = t & 15;
    *(bf16x8*)&xs[buf * 8448 + row * 128 + sl * 8] =
        bf16x8{(__bf16)0.f,(__bf16)0.f,(__bf16)0.f,(__bf16)0.f,
               (__bf16)0.f,(__bf16)0.f,(__bf16)0.f,(__bf16)0.f};
  }

  // per-lane A-frag LDS byte offsets [tap][kt]; buffer/mtile go in imm
  int aoff[3][4];
#pragma unroll
  for (int tap = 0; tap < 3; ++tap) {
    const int rr = lo16 + tap;
#pragma unroll
    for (int kt = 0; kt < 4; ++kt)
      aoff[tap][kt] = rr * 256 + ((((kt << 2) + g16) ^ (rr & 7)) << 4);
  }
  const char* xsb = (const char*)xs;

  // DMA one segment (64 rows) into buffer bufsel; 4 issues/wave x 4 waves.
  // lane l of issue q writes LDS (row 4q + l/16, slot l&15); source picks the
  // logical column (l&15)^(r&7) so LDS ends up swizzled.  Rows clamped to
  // Tm1 (beyond-segment rows hold neighbor data -> finite, sentinel-masked).
  auto stage = [&](int off_n, int bufsel) {
    __bf16* lb = &xs[bufsel * 8448];
    const int rl = lane >> 4, cl = lane & 15;
#pragma unroll
    for (int i = 0; i < 4; ++i) {
      const int q = (wid << 2) + i;
      const int r = (q << 2) + rl;
      const int grow = min(off_n + r, Tm1);
      const __bf16* src = xb + (size_t)grow * 128 + ((cl ^ (r & 7)) << 3);
      GLD_LDS16(src, lb + q * 512);
    }
  };

  stage(offsets[b0], 0);

  for (int g = 0; g < 8; ++g) {
    const int bufoff = (g & 1) * 16896;
    // drains THIS segment's DMAs (prefetch for g+1 not yet issued) and
    // guarantees all waves are done reading the buffer we're about to fill
    __syncthreads();
    if (g < 7) stage(offsets[b0 + g + 1], (g + 1) & 1);

    const int b = b0 + g;
    const int s = sizes[b];
    const int MT = (s + 15) >> 4;     // 1..4

#pragma unroll
    for (int fi = 0; fi < 2; ++fi) {
      const int ft = wid + (fi << 2);
      const int feat = ft * 16 + lo16;

      // sentinel init: 0 on valid rows of pool p, -1e30 elsewhere
      f32x4 acc[4][3];
#pragma unroll
      for (int mt = 0; mt < 4; ++mt)
#pragma unroll
        for (int p = 0; p < 3; ++p)
#pragma unroll
          for (int v = 0; v < 4; ++v)
            acc[mt][p][v] = (mt * 16 + g16 * 4 + v < s - p) ? 0.f : -1e30f;

#pragma unroll
      for (int kt = 0; kt < 4; ++kt) {
        // slices: 0=w1j0, 1=w2j0, 2=w2j1, 3=w3j0, 4=w3j1, 5=w3j2
        const int bbase = ((ft * 4 + kt) << 6) + lane;
        const bf16x8 bf0 = Wpack[bbase];
        const bf16x8 bf1 = Wpack[bbase + 2048];
        const bf16x8 bf2 = Wpack[bbase + 4096];
        const bf16x8 bf3 = Wpack[bbase + 6144];
        const bf16x8 bf4 = Wpack[bbase + 8192];
        const bf16x8 bf5 = Wpack[bbase + 10240];
#pragma unroll
        for (int mt = 0; mt < 4; ++mt) {
          if (mt < MT) {   // uniform per block
            const int ab = bufoff + mt * 4096;
            const bf16x8 A0 = *(const bf16x8*)(xsb + ab + aoff[0][kt]);
            const bf16x8 A1 = *(const bf16x8*)(xsb + ab + aoff[1][kt]);
            const bf16x8 A2 = *(const bf16x8*)(xsb + ab + aoff[2][kt]);
            acc[mt][0] = MFMA16(A0, bf0, acc[mt][0]);
            acc[mt][1] = MFMA16(A0, bf1, acc[mt][1]);
            acc[mt][1] = MFMA16(A1, bf2, acc[mt][1]);
            acc[mt][2] = MFMA16(A0, bf3, acc[mt][2]);
            acc[mt][2] = MFMA16(A1, bf4, acc[mt][2]);
            acc[mt][2] = MFMA16(A2, bf5, acc[mt][2]);
          }
        }
      }

      // epilogue: unpredicated max (sentinels mask invalid rows/tiles)
      float m[3];
#pragma unroll
      for (int p = 0; p < 3; ++p) {
        float mm = fmaxf(fmaxf(acc[0][p][0], acc[0][p][1]),
                         fmaxf(acc[0][p][2], acc[0][p][3]));
#pragma unroll
        for (int mt = 1; mt < 4; ++mt)
          mm = fmaxf(mm, fmaxf(fmaxf(acc[mt][p][0], acc[mt][p][1]),
                               fmaxf(acc[mt][p][2], acc[mt][p][3])));
        mm = fmaxf(mm, __shfl_xor(mm, 16));
        mm = fmaxf(mm, __shfl_xor(mm, 32));
        m[p] = mm;
      }
      if (g16 == 0) {
        // max(relu(h)) == relu(max(Y)+b): bias row-constant, relu monotone
        const float p1 = fmaxf(m[0] + cb0[feat], 0.f);
        const float p2 = fmaxf(m[1] + cb1[feat], 0.f);
        const float p3 = fmaxf(m[2] + cb2[feat], 0.f);
        const __bf16 h1 = (__bf16)p1, h2 = (__bf16)p2, h3 = (__bf16)p3;
        const long row = (long)b * 384;
        Phi[row + feat]       = h1;
        Plo[row + feat]       = (__bf16)(p1 - (float)h1);
        Phi[row + 128 + feat] = h2;
        Plo[row + 128 + feat] = (__bf16)(p2 - (float)h2);
        Phi[row + 256 + feat] = h3;
        Plo[row + 256 + feat] = (__bf16)(p3 - (float)h3);
      }
    }
  }
}

// ---------------------------------------------------------------------------
// K3: out = tanh(P[8192,384] @ lin_w^T + lin_b), split bf16 MFMA (3 products:
// Ph*Wh + Pl*Wh + Ph*Wl -> ~fp32 accuracy).  512 blocks x 16 batch rows.
// ---------------------------------------------------------------------------
__global__ __launch_bounds__(256, 4)
void k_lin(const __bf16* __restrict__ Phi, const __bf16* __restrict__ Plo,
           const bf16x8* __restrict__ Lhi, const bf16x8* __restrict__ Llo,
           const float* __restrict__ lb, float* __restrict__ out) {
  __shared__ __bf16 ph[16 * 392];   // [row][384 + 8 pad]
  __shared__ __bf16 pl[16 * 392];
  const int blk = blockIdx.x, t = threadIdx.x;
  const long rbase = (long)blk * 16;
#pragma unroll
  for (int i = 0; i < 3; ++i) {
    const int ci = t + (i << 8);
    const int r = ci / 48, cc = ci % 48;
    *(int4*)&ph[r * 392 + (cc << 3)] = *(const int4*)&Phi[(rbase + r) * 384 + (cc << 3)];
    *(int4*)&pl[r * 392 + (cc << 3)] = *(const int4*)&Plo[(rbase + r) * 384 + (cc << 3)];
  }
  __syncthreads();
  const int wid = t >> 6, lane = t & 63;
  const int lo16 = lane & 15, g = lane >> 4;
#pragma unroll
  for (int ni = 0; ni < 2; ++ni) {
    const int nt = wid + (ni << 2);
    f32x4 acc = f32x4{0.f, 0.f, 0.f, 0.f};
#pragma unroll
    for (int kt = 0; kt < 12; ++kt) {
      const bf16x8 bh = Lhi[((nt * 12 + kt) << 6) + lane];
      const bf16x8 bl = Llo[((nt * 12 + kt) << 6) + lane];
      const int aoff = lo16 * 392 + kt * 32 + (g << 3);
      const bf16x8 ah = *(const bf16x8*)&ph[aoff];
      const bf16x8 al = *(const bf16x8*)&pl[aoff];
      acc = MFMA16(ah, bh, acc);
      acc = MFMA16(al, bh, acc);
      acc = MFMA16(ah, bl, acc);
    }
    const int o = nt * 16 + lo16;
    const float bias = lb[o];
#pragma unroll
    for (int v = 0; v < 4; ++v) {
      const int r = g * 4 + v;
      const float val = acc[v] + bias;
      out[(rbase + r) * 128 + o] = 1.f - 2.f / (__expf(2.f * val) + 1.f);
    }
  }
}

// ---------------------------------------------------------------------------
extern "C" void kernel_launch(void* const* d_in, const int* in_sizes, int n_in,
                              void* d_out, int out_size, void* d_ws, size_t ws_size,
                              hipStream_t stream) {
  const float* x   = (const float*)d_in[0];
  const int* sizes = (const int*)d_in[1];
  const float* w0  = (const float*)d_in[2];
  const float* cb0 = (const float*)d_in[3];
  const float* w1  = (const float*)d_in[4];
  const float* cb1 = (const float*)d_in[5];
  const float* w2  = (const float*)d_in[6];
  const float* cb2 = (const float*)d_in[7];
  const float* lw  = (const float*)d_in[8];
  const float* lb  = (const float*)d_in[9];

  const int nx = in_sizes[0];          // total * 128
  const int T  = nx / 128;

  char* ws = (char*)d_ws;
  size_t o = 0;
  int*    offsets = (int*)ws;                 o += 32768;
  __bf16* Wpack   = (__bf16*)(ws + o);        o += 196608;     // 48*4*64*8*2
  __bf16* Lhi     = (__bf16*)(ws + o);        o += 98304;      // 8*12*64*8*2
  __bf16* Llo     = (__bf16*)(ws + o);        o += 98304;
  __bf16* Phi     = (__bf16*)(ws + o);        o += 8192L * 384 * 2;
  __bf16* Plo     = (__bf16*)(ws + o);        o += 8192L * 384 * 2;
  __bf16* xbuf    = (__bf16*)(ws + o);        o += (size_t)nx * 2;

  k_prep<<<2048, 256, 0, stream>>>(sizes, offsets, w0, w1, w2, lw,
                                   x, xbuf, nx, Wpack, Lhi, Llo);
  k_conv<<<1024, 256, 0, stream>>>(xbuf, sizes, offsets, T - 1,
                                   cb0, cb1, cb2, (const bf16x8*)Wpack, Phi, Plo);
  k_lin<<<512, 256, 0, stream>>>(Phi, Plo, (const bf16x8*)Lhi,
                                 (const bf16x8*)Llo, lb, (float*)d_out);
}